// Round 8
// baseline (14840.646 us; speedup 1.0000x reference)
//
#include <hip/hip_runtime.h>
#include <hip/hip_cooperative_groups.h>
#include <stdint.h>

namespace cg = cooperative_groups;

// Problem dims
#define Tn 512
#define Bn 128
#define NTOK (Bn*Tn)     // 65536
#define En 300
#define Hn 300
#define On 9
#define KP 320           // K padded to 10*32
#define LDK 328          // LDS row stride in shorts (656 B rows = 41*16, keeps 16B alignment)
#define HS 12            // hidden units per slice
#define NSL 25           // slices per direction (25*12 = 300)
#define NCH 4            // batch chunks
#define MC 32            // batch rows per chunk
#define NG 48            // 4*HS gate columns per block
#define NBLK (2*NCH*NSL) // 200 blocks (proven co-resident: rounds 3/4/6/7 completed)
#define NTHR 384

typedef short s4v __attribute__((ext_vector_type(4)));
typedef short s8v __attribute__((ext_vector_type(8)));
typedef float f4v __attribute__((ext_vector_type(4)));

// ---- static device scratch (d_ws unused). Zeroed every call by k_zero. ----
__device__ float          g_logits[NTOK * On];        // 2,359,296 B
__device__ unsigned short g_hx[2 * 2 * Bn * KP];      //   327,680 B  [dir][slot][Bn][KP]

__device__ inline float b2f(unsigned short u){ unsigned v = ((unsigned)u) << 16; float f; __builtin_memcpy(&f, &v, 4); return f; }
__device__ inline unsigned short f2b(float f){ unsigned u; __builtin_memcpy(&u, &f, 4); u = u + 0x7fffu + ((u >> 16) & 1u); return (unsigned short)(u >> 16); }
__device__ inline float sigf(float x){ return 1.f / (1.f + __expf(-x)); }
__device__ inline float tanh_f(float x){ return 2.f / (1.f + __expf(-2.f * x)) - 1.f; }

// ---------------- K0: zero the static scratch (capture-safe, every call) ----------------
__global__ __launch_bounds__(256) void k_zero()
{
    const int i = blockIdx.x * 256 + threadIdx.x;
    const int stride = gridDim.x * 256;
    for (int j = i; j < NTOK * On; j += stride) g_logits[j] = 0.f;
    unsigned int* hp = (unsigned int*)g_hx;
    for (int j = i; j < (2 * 2 * Bn * KP) / 2; j += stride) hp[j] = 0u;
}

// ---------------- K1: fused bidirectional LSTM recurrence (cooperative, MFMA gates) ----------------
__global__ __launch_bounds__(NTHR) void k_lstm(
    const int* __restrict__ x, const float* __restrict__ emb,
    const float* __restrict__ W_ih_f, const float* __restrict__ W_hh_f, const float* __restrict__ b_f,
    const float* __restrict__ W_ih_b, const float* __restrict__ W_hh_b, const float* __restrict__ b_b,
    const float* __restrict__ W_lin)
{
    cg::grid_group gg = cg::this_grid();

    const int bi    = blockIdx.x;
    const int dir   = bi / (NCH * NSL);
    const int rem   = bi % (NCH * NSL);
    const int chunk = rem / NSL;
    const int slice = rem % NSL;
    const int j0    = slice * HS;
    const int b0    = chunk * MC;

    const float* Wih  = dir ? W_ih_b : W_ih_f;
    const float* Whh  = dir ? W_hh_b : W_hh_f;
    const float* bias = dir ? b_b    : b_f;
    unsigned short* hxd = g_hx + dir * (2 * Bn * KP);

    __shared__ __align__(16) unsigned short Asm[MC * LDK]; // 20.5 KB A-staging (emb, then h), bf16
    __shared__ __align__(16) float Gsm[MC * NG];           // 6 KB gate dump
    __shared__ __align__(16) float Hsm[MC * HS];           // 1.5 KB h (fp32) for out-proj
    __shared__ __align__(16) float WlS[On * HS];           // 432 B W_lin slice (fp32)

    const int tid  = threadIdx.x;
    const int lane = tid & 63;
    const int wid  = tid >> 6;              // 6 waves
    const int m0   = (wid & 1) * 16;        // 2 m-tiles
    const int n0   = (wid >> 1) * 16;       // 3 n-tiles
    const int kq   = (lane >> 4) * 8;       // k-subgroup within 32

    // W_lin slice for this block's 12 hidden columns (dir offset), fp32
    if (tid < On * HS) {
        int o = tid / HS, jj = tid % HS;
        WlS[tid] = W_lin[o * (2 * Hn) + dir * Hn + j0 + jj];
    }

    // ---- preload weight B-fragments (fp32 -> bf16 once, weight-stationary) ----
    // local gate col layout: [i(12) | f(12) | g(12) | o(12)]
    const int nloc = n0 + (lane & 15);
    const int q    = nloc / HS;
    const int jjn  = nloc % HS;
    const int grow = q * Hn + j0 + jjn;     // global row in [1200]
    s8v bih[10], bhh[10];
#pragma unroll
    for (int kc = 0; kc < 10; kc++) {
        int kb = kc * 32 + kq;
        s8v fi = {0,0,0,0,0,0,0,0}, fh = {0,0,0,0,0,0,0,0};
#pragma unroll
        for (int j = 0; j < 8; j++) {
            int k = kb + j;
            if (k < En) {
                fi[j] = (short)f2b(Wih[grow * En + k]);
                fh[j] = (short)f2b(Whh[grow * Hn + k]);
            }
        }
        bih[kc] = fi; bhh[kc] = fh;
    }

    // ---- per-thread cell state: tid <-> (batch row ebl, unit ejj); NTHR == MC*HS ----
    const int ebl = tid / HS;   // 0..31
    const int ejj = tid % HS;   // 0..11
    const float bi_i = bias[0 * Hn + j0 + ejj];
    const float bi_f = bias[1 * Hn + j0 + ejj];
    const float bi_g = bias[2 * Hn + j0 + ejj];
    const float bi_o = bias[3 * Hn + j0 + ejj];
    float creg = 0.f;

    __syncthreads();   // WlS visible

#pragma unroll 1
    for (int s = 0; s < Tn; s++) {
        const int t = dir ? (Tn - 1 - s) : s;

        // P1: stage emb rows for step t (fp32 -> bf16; cols 300..319 zero)
        for (int i = tid; i < MC * 80; i += NTHR) {
            int r = i / 80, c = i - r * 80;
            s4v v = {0, 0, 0, 0};
            if (c < 75) {
                int xi = x[(b0 + r) * Tn + t];
                float4 f = *(const float4*)(emb + (size_t)xi * En + c * 4);
                v[0] = (short)f2b(f.x); v[1] = (short)f2b(f.y);
                v[2] = (short)f2b(f.z); v[3] = (short)f2b(f.w);
            }
            *(s4v*)&Asm[r * LDK + c * 4] = v;
        }
        __syncthreads();

        // MFMA1: input projection part
        f4v acc = {0.f, 0.f, 0.f, 0.f};
        {
            const unsigned short* abase = &Asm[(m0 + (lane & 15)) * LDK + kq];
#pragma unroll
            for (int kc = 0; kc < 10; kc++) {
                s8v a = *(const s8v*)(abase + kc * 32);
                acc = __builtin_amdgcn_mfma_f32_16x16x32_bf16(a, bih[kc], acc, 0, 0, 0);
            }
        }

        __syncthreads();          // all waves done reading Asm (emb)
        gg.sync();                // h_s published by every block, device-visible

        // P3: stage h_s from parity slot; clamp |h|>1 (no-op for correct h, insurance)
        {
            const unsigned short* hsrc = hxd + (s & 1) * (Bn * KP) + b0 * KP;
            for (int i = tid; i < MC * 40; i += NTHR) {
                int r = i / 40, c = i - r * 40;
                s8v v = *(const s8v*)(hsrc + r * KP + c * 8);
#pragma unroll
                for (int j = 0; j < 8; j++) {
                    unsigned short u = (unsigned short)v[j];
                    unsigned short a = u & 0x7FFF;
                    if (a > 0x3F80) u = (u & 0x8000) | 0x3F80;
                    v[j] = (short)u;
                }
                *(s8v*)&Asm[r * LDK + c * 8] = v;
            }
        }
        __syncthreads();

        // MFMA2: recurrent part
        {
            const unsigned short* abase = &Asm[(m0 + (lane & 15)) * LDK + kq];
#pragma unroll
            for (int kc = 0; kc < 10; kc++) {
                s8v a = *(const s8v*)(abase + kc * 32);
                acc = __builtin_amdgcn_mfma_f32_16x16x32_bf16(a, bhh[kc], acc, 0, 0, 0);
            }
        }

        // dump gates (C layout: col=lane&15, row=(lane>>4)*4+reg)
        {
            int col   = n0 + (lane & 15);
            int rbase = m0 + (lane >> 4) * 4;
#pragma unroll
            for (int r2 = 0; r2 < 4; r2++) Gsm[(rbase + r2) * NG + col] = acc[r2];
        }
        __syncthreads();

        // elementwise LSTM cell
        {
            float gi  = Gsm[ebl * NG + 0 * HS + ejj] + bi_i;
            float gf  = Gsm[ebl * NG + 1 * HS + ejj] + bi_f;
            float gg2 = Gsm[ebl * NG + 2 * HS + ejj] + bi_g;
            float go  = Gsm[ebl * NG + 3 * HS + ejj] + bi_o;
            float iv = sigf(gi), fv = sigf(gf), gv = tanh_f(gg2), ov = sigf(go);
            creg = fv * creg + iv * gv;
            float h = ov * tanh_f(creg);
            Hsm[ebl * HS + ejj] = h;
            // publish h_{s+1} (other parity slot); visibility via next gg.sync
            hxd[((s + 1) & 1) * (Bn * KP) + (b0 + ebl) * KP + (j0 + ejj)] = f2b(h);
        }
        __syncthreads();

        // out-projection contribution: 32 rows x 9 outputs, 12-dim fp32 dots
        if (tid < MC * On) {
            int r = tid / On, o = tid - r * On;
            float p = 0.f;
#pragma unroll
            for (int jj = 0; jj < HS; jj++) p += Hsm[r * HS + jj] * WlS[o * HS + jj];
            atomicAdd(&g_logits[((size_t)((b0 + r) * Tn + t)) * On + o], p);
        }
        // no barrier needed: Hsm next written only after barriers in next iter
    }
}

// ---------------- K2: bias + softmax over 9 classes, FP32 writeout ----------------
__global__ __launch_bounds__(256) void k_softmax(
    const float* __restrict__ b_lin, float* __restrict__ out)
{
    const int p = blockIdx.x * 256 + threadIdx.x;   // 0..65535
    float lg[On];
    float m = -1e30f;
#pragma unroll
    for (int o = 0; o < On; o++) {
        lg[o] = g_logits[(size_t)p * On + o] + b_lin[o];
        m = fmaxf(m, lg[o]);
    }
    float ssum = 0.f;
#pragma unroll
    for (int o = 0; o < On; o++) { lg[o] = __expf(lg[o] - m); ssum += lg[o]; }
    float inv = 1.f / ssum;
#pragma unroll
    for (int o = 0; o < On; o++) out[(size_t)p * On + o] = lg[o] * inv;
}

// ---------------- host launcher ----------------
extern "C" void kernel_launch(void* const* d_in, const int* in_sizes, int n_in,
                              void* d_out, int out_size, void* d_ws, size_t ws_size,
                              hipStream_t stream)
{
    (void)in_sizes; (void)n_in; (void)out_size; (void)d_ws; (void)ws_size;
    const int* x = (const int*)d_in[0];
    const float* emb   = (const float*)d_in[1];
    const float* Wih_f = (const float*)d_in[2];
    const float* Whh_f = (const float*)d_in[3];
    const float* bf    = (const float*)d_in[4];
    const float* Wih_b = (const float*)d_in[5];
    const float* Whh_b = (const float*)d_in[6];
    const float* bb    = (const float*)d_in[7];
    const float* Wlin  = (const float*)d_in[8];
    const float* blin  = (const float*)d_in[9];
    float* out = (float*)d_out;                    // reference output dtype: float32

    // zero static scratch (logits + h ring)
    k_zero<<<512, 256, 0, stream>>>();

    void* args[] = {
        (void*)&x, (void*)&emb,
        (void*)&Wih_f, (void*)&Whh_f, (void*)&bf,
        (void*)&Wih_b, (void*)&Whh_b, (void*)&bb,
        (void*)&Wlin
    };
    hipLaunchCooperativeKernel((const void*)k_lstm, dim3(NBLK), dim3(NTHR), args, 0, stream);

    k_softmax<<<NTOK / 256, 256, 0, stream>>>(blin, out);
}

// Round 9
// 6144.946 us; speedup vs baseline: 2.4151x; 2.4151x over previous
//
#include <hip/hip_runtime.h>
#include <stdint.h>

// Problem dims
#define Tn 512
#define Bn 128
#define NTOK (Bn*Tn)     // 65536
#define En 300
#define Hn 300
#define On 9
#define KP 320           // K padded to 10*32
#define LDK 328          // LDS row stride in shorts (656 B rows, 16B-aligned)
#define HS 12            // hidden units per slice
#define NSL 25           // slices per direction (25*12 = 300)
#define NCH 4            // batch chunks
#define MC 32            // batch rows per chunk
#define NG 48            // 4*HS gate columns per block
#define NBLK (2*NCH*NSL) // 200 blocks (proven co-resident envelope)
#define NTHR 384

typedef short s4v __attribute__((ext_vector_type(4)));
typedef short s8v __attribute__((ext_vector_type(8)));
typedef float f4v __attribute__((ext_vector_type(4)));

// ---- static device scratch (d_ws unused) ----
__device__ unsigned short g_hcat[NTOK * 2 * Hn];   // 78,643,200 B — h outputs, fully overwritten each call
__device__ unsigned short g_hx[2 * 2 * Bn * KP];   //    327,680 B — [dir][slot][Bn][KP] h exchange
__device__ int            g_flags[2 * NCH * NSL];  //        800 B — per-(dir,chunk) slice flags

__device__ inline float b2f(unsigned short u){ unsigned v = ((unsigned)u) << 16; float f; __builtin_memcpy(&f, &v, 4); return f; }
__device__ inline unsigned short f2b(float f){ unsigned u; __builtin_memcpy(&u, &f, 4); u = u + 0x7fffu + ((u >> 16) & 1u); return (unsigned short)(u >> 16); }
__device__ inline float sigf(float x){ return 1.f / (1.f + __expf(-x)); }
__device__ inline float tanh_f(float x){ return 2.f / (1.f + __expf(-2.f * x)) - 1.f; }

// ---------------- K0: zero h-exchange + flags (capture-safe, every call) ----------------
__global__ __launch_bounds__(256) void k_zero()
{
    const int i = blockIdx.x * 256 + threadIdx.x;
    const int stride = gridDim.x * 256;
    unsigned int* hp = (unsigned int*)g_hx;
    for (int j = i; j < (2 * 2 * Bn * KP) / 2; j += stride) hp[j] = 0u;
    for (int j = i; j < 2 * NCH * NSL; j += stride) g_flags[j] = 0;
}

// ---------------- K1: fused bidirectional LSTM recurrence ----------------
// Cooperative launch for co-residency; sync via per-(dir,chunk) flag groups
// (25 blocks each) with AGENT-scope LLC-coherent h exchange — NO grid.sync,
// so per-XCD L2s are never flushed (emb staging stays L2-resident).
__global__ __launch_bounds__(NTHR) void k_lstm(
    const int* __restrict__ x, const float* __restrict__ emb,
    const float* __restrict__ W_ih_f, const float* __restrict__ W_hh_f, const float* __restrict__ b_f,
    const float* __restrict__ W_ih_b, const float* __restrict__ W_hh_b, const float* __restrict__ b_b)
{
    const int bi    = blockIdx.x;
    const int dir   = bi / (NCH * NSL);
    const int rem   = bi % (NCH * NSL);
    const int chunk = rem / NSL;
    const int slice = rem % NSL;
    const int j0    = slice * HS;
    const int b0    = chunk * MC;

    const float* Wih  = dir ? W_ih_b : W_ih_f;
    const float* Whh  = dir ? W_hh_b : W_hh_f;
    const float* bias = dir ? b_b    : b_f;
    unsigned short* hxd = g_hx + dir * (2 * Bn * KP);
    int* myf = g_flags + (dir * NCH + chunk) * NSL;

    __shared__ __align__(16) unsigned short Asm[MC * LDK]; // 20.5 KB A-staging (emb, then h), bf16
    __shared__ __align__(16) float Gsm[MC * NG];           // 6 KB gate dump
    __shared__ __align__(16) float Hsm[MC * HS];           // 1.5 KB h (fp32) for publish repack

    const int tid  = threadIdx.x;
    const int lane = tid & 63;
    const int wid  = tid >> 6;              // 6 waves
    const int m0   = (wid & 1) * 16;        // 2 m-tiles
    const int n0   = (wid >> 1) * 16;       // 3 n-tiles
    const int kq   = (lane >> 4) * 8;       // k-subgroup within 32

    // ---- preload weight B-fragments (fp32 -> bf16 once, weight-stationary) ----
    const int nloc = n0 + (lane & 15);
    const int q    = nloc / HS;
    const int jjn  = nloc % HS;
    const int grow = q * Hn + j0 + jjn;     // global row in [1200]
    s8v bih[10], bhh[10];
#pragma unroll
    for (int kc = 0; kc < 10; kc++) {
        int kb = kc * 32 + kq;
        s8v fi = {0,0,0,0,0,0,0,0}, fh = {0,0,0,0,0,0,0,0};
#pragma unroll
        for (int j = 0; j < 8; j++) {
            int k = kb + j;
            if (k < En) {
                fi[j] = (short)f2b(Wih[grow * En + k]);
                fh[j] = (short)f2b(Whh[grow * Hn + k]);
            }
        }
        bih[kc] = fi; bhh[kc] = fh;
    }

    // ---- per-thread cell state: tid <-> (batch row ebl, unit ejj); NTHR == MC*HS ----
    const int ebl = tid / HS;   // 0..31
    const int ejj = tid % HS;   // 0..11
    const float bi_i = bias[0 * Hn + j0 + ejj];
    const float bi_f = bias[1 * Hn + j0 + ejj];
    const float bi_g = bias[2 * Hn + j0 + ejj];
    const float bi_o = bias[3 * Hn + j0 + ejj];
    float creg = 0.f;

#pragma unroll 1
    for (int s = 0; s < Tn; s++) {
        const int t = dir ? (Tn - 1 - s) : s;

        // P1: stage emb rows for step t (fp32 -> bf16; cols 300..319 zero) — off critical path
        for (int i = tid; i < MC * 80; i += NTHR) {
            int r = i / 80, c = i - r * 80;
            s4v v = {0, 0, 0, 0};
            if (c < 75) {
                int xi = x[(b0 + r) * Tn + t];
                float4 f = *(const float4*)(emb + (size_t)xi * En + c * 4);
                v[0] = (short)f2b(f.x); v[1] = (short)f2b(f.y);
                v[2] = (short)f2b(f.z); v[3] = (short)f2b(f.w);
            }
            *(s4v*)&Asm[r * LDK + c * 4] = v;
        }
        __syncthreads();

        // MFMA1: input projection part (h-independent, overlaps other groups' latency)
        f4v acc = {0.f, 0.f, 0.f, 0.f};
        {
            const unsigned short* abase = &Asm[(m0 + (lane & 15)) * LDK + kq];
#pragma unroll
            for (int kc = 0; kc < 10; kc++) {
                s8v a = *(const s8v*)(abase + kc * 32);
                acc = __builtin_amdgcn_mfma_f32_16x16x32_bf16(a, bih[kc], acc, 0, 0, 0);
            }
        }

        // wait: all 25 slices of this (dir,chunk) group have published h_s
        if (wid == 0 && lane < NSL) {
            while (__hip_atomic_load(&myf[lane], __ATOMIC_RELAXED, __HIP_MEMORY_SCOPE_AGENT) < s) {
                __builtin_amdgcn_s_sleep(1);
            }
        }
        __syncthreads();   // also separates MFMA1's Asm reads from P3's Asm writes

        // P3: stage h_s from parity slot (LLC-coherent dword loads)
        {
            const unsigned short* hsrc = hxd + (s & 1) * (Bn * KP) + b0 * KP;
            for (int i = tid; i < MC * 160; i += NTHR) {
                int r = i / 160, c = i - r * 160;
                unsigned int v = __hip_atomic_load((const unsigned int*)(hsrc + r * KP) + c,
                                                   __ATOMIC_RELAXED, __HIP_MEMORY_SCOPE_AGENT);
                *(unsigned int*)&Asm[r * LDK + c * 2] = v;
            }
        }
        __syncthreads();

        // MFMA2: recurrent part
        {
            const unsigned short* abase = &Asm[(m0 + (lane & 15)) * LDK + kq];
#pragma unroll
            for (int kc = 0; kc < 10; kc++) {
                s8v a = *(const s8v*)(abase + kc * 32);
                acc = __builtin_amdgcn_mfma_f32_16x16x32_bf16(a, bhh[kc], acc, 0, 0, 0);
            }
        }

        // dump gates (C layout: col=lane&15, row=(lane>>4)*4+reg)
        {
            int col   = n0 + (lane & 15);
            int rbase = m0 + (lane >> 4) * 4;
#pragma unroll
            for (int r2 = 0; r2 < 4; r2++) Gsm[(rbase + r2) * NG + col] = acc[r2];
        }
        __syncthreads();

        // elementwise LSTM cell; h to LDS (for publish) and g_hcat (plain store, fire-and-forget)
        {
            float gi  = Gsm[ebl * NG + 0 * HS + ejj] + bi_i;
            float gf  = Gsm[ebl * NG + 1 * HS + ejj] + bi_f;
            float gg2 = Gsm[ebl * NG + 2 * HS + ejj] + bi_g;
            float go  = Gsm[ebl * NG + 3 * HS + ejj] + bi_o;
            float iv = sigf(gi), fv = sigf(gf), gv = tanh_f(gg2), ov = sigf(go);
            creg = fv * creg + iv * gv;
            float h = ov * tanh_f(creg);
            Hsm[ebl * HS + ejj] = h;
            g_hcat[((size_t)((b0 + ebl) * Tn + t)) * (2 * Hn) + dir * Hn + (j0 + ejj)] = f2b(h);
        }
        __syncthreads();

        // publish h_{s+1} into other parity slot as 32-bit words (slice owns 6 words/row)
        if (tid < MC * (HS / 2)) {   // 192 threads
            int r = tid / (HS / 2), w = tid % (HS / 2);
            unsigned int lo = f2b(Hsm[r * HS + 2 * w]);
            unsigned int hi = f2b(Hsm[r * HS + 2 * w + 1]);
            __hip_atomic_store((unsigned int*)(hxd + ((s + 1) & 1) * (Bn * KP)) + (b0 + r) * (KP / 2) + (j0 / 2 + w),
                               lo | (hi << 16), __ATOMIC_RELAXED, __HIP_MEMORY_SCOPE_AGENT);
        }
        __syncthreads();   // each wave drains vmcnt at barrier -> h stores at LLC

        if (tid == 0) {
            __hip_atomic_store(&myf[slice], s + 1, __ATOMIC_RELEASE, __HIP_MEMORY_SCOPE_AGENT);
        }
    }
}

// ---------------- K2: fused out-projection + softmax, one wave per 16 positions ----------------
__global__ __launch_bounds__(256) void k_out(
    const float* __restrict__ W_lin, const float* __restrict__ b_lin, float* __restrict__ out)
{
    __shared__ float Wl[On * 2 * Hn];  // 21.6 KB
    __shared__ float bl[On];
    const int tid = threadIdx.x;
    for (int i = tid; i < On * 2 * Hn; i += 256) Wl[i] = W_lin[i];
    if (tid < On) bl[tid] = b_lin[tid];
    __syncthreads();

    const int lane = tid & 63;
    const int w    = tid >> 6;
    const int wg   = blockIdx.x * 4 + w;      // 4096 waves
    for (int it = 0; it < 16; it++) {
        const int p = wg * 16 + it;           // 0..65535
        const unsigned short* row = g_hcat + (size_t)p * (2 * Hn);
        float part[On];
#pragma unroll
        for (int o = 0; o < On; o++) part[o] = 0.f;
        for (int c = 0; c < 10; c++) {
            int k = lane + 64 * c;
            if (k < 2 * Hn) {
                float v = b2f(row[k]);
#pragma unroll
                for (int o = 0; o < On; o++) part[o] += v * Wl[o * (2 * Hn) + k];
            }
        }
#pragma unroll
        for (int off = 32; off >= 1; off >>= 1) {
#pragma unroll
            for (int o = 0; o < On; o++) part[o] += __shfl_xor(part[o], off, 64);
        }
        if (lane == 0) {
            float lg[On];
            float m = -1e30f;
#pragma unroll
            for (int o = 0; o < On; o++) { lg[o] = part[o] + bl[o]; m = fmaxf(m, lg[o]); }
            float ssum = 0.f;
#pragma unroll
            for (int o = 0; o < On; o++) { lg[o] = __expf(lg[o] - m); ssum += lg[o]; }
            float inv = 1.f / ssum;
#pragma unroll
            for (int o = 0; o < On; o++) out[(size_t)p * On + o] = lg[o] * inv;
        }
    }
}

// ---------------- host launcher ----------------
extern "C" void kernel_launch(void* const* d_in, const int* in_sizes, int n_in,
                              void* d_out, int out_size, void* d_ws, size_t ws_size,
                              hipStream_t stream)
{
    (void)in_sizes; (void)n_in; (void)out_size; (void)d_ws; (void)ws_size;
    const int* x = (const int*)d_in[0];
    const float* emb   = (const float*)d_in[1];
    const float* Wih_f = (const float*)d_in[2];
    const float* Whh_f = (const float*)d_in[3];
    const float* bf    = (const float*)d_in[4];
    const float* Wih_b = (const float*)d_in[5];
    const float* Whh_b = (const float*)d_in[6];
    const float* bb    = (const float*)d_in[7];
    const float* Wlin  = (const float*)d_in[8];
    const float* blin  = (const float*)d_in[9];
    float* out = (float*)d_out;

    k_zero<<<128, 256, 0, stream>>>();

    void* args[] = {
        (void*)&x, (void*)&emb,
        (void*)&Wih_f, (void*)&Whh_f, (void*)&bf,
        (void*)&Wih_b, (void*)&Whh_b, (void*)&bb
    };
    hipLaunchCooperativeKernel((const void*)k_lstm, dim3(NBLK), dim3(NTHR), args, 0, stream);

    k_out<<<1024, 256, 0, stream>>>(Wlin, blin, out);
}

// Round 10
// 3867.960 us; speedup vs baseline: 3.8368x; 1.5887x over previous
//
#include <hip/hip_runtime.h>
#include <stdint.h>

// Problem dims
#define Tn 512
#define Bn 128
#define NTOK (Bn*Tn)     // 65536
#define En 300
#define Hn 300
#define On 9
#define KP 320           // K padded to 10*32
#define LDK 328          // LDS row stride in shorts (656 B rows, 16B-aligned)
#define HS 20            // hidden units per slice
#define NSL 15           // slices per direction (15*20 = 300)
#define NCH 4            // batch chunks
#define MC 32            // batch rows per chunk
#define NG 80            // 4*HS gate columns per block
#define NBLK (2*NCH*NSL) // 120 blocks
#define NTHR 640         // 10 waves = 2 m-tiles x 5 n-tiles; == MC*HS cell threads

typedef short s4v __attribute__((ext_vector_type(4)));
typedef short s8v __attribute__((ext_vector_type(8)));
typedef float f4v __attribute__((ext_vector_type(4)));

// ---- static device scratch (d_ws unused) ----
__device__ unsigned short g_hcat[NTOK * 2 * Hn];   // 78,643,200 B — h outputs
__device__ unsigned short g_hx[2 * 2 * Bn * KP];   //    327,680 B — [dir][slot][Bn][KP]
__device__ int            g_flags[2 * NCH * NSL];  //        480 B — per-(dir,chunk) slice flags

__device__ inline float b2f(unsigned short u){ unsigned v = ((unsigned)u) << 16; float f; __builtin_memcpy(&f, &v, 4); return f; }
__device__ inline unsigned short f2b(float f){ unsigned u; __builtin_memcpy(&u, &f, 4); u = u + 0x7fffu + ((u >> 16) & 1u); return (unsigned short)(u >> 16); }
__device__ inline float sigf(float x){ return 1.f / (1.f + __expf(-x)); }
__device__ inline float tanh_f(float x){ return 2.f / (1.f + __expf(-2.f * x)) - 1.f; }

// ---------------- K0: zero h-exchange + flags ----------------
__global__ __launch_bounds__(256) void k_zero()
{
    const int i = blockIdx.x * 256 + threadIdx.x;
    const int stride = gridDim.x * 256;
    unsigned int* hp = (unsigned int*)g_hx;
    for (int j = i; j < (2 * 2 * Bn * KP) / 2; j += stride) hp[j] = 0u;
    for (int j = i; j < 2 * NCH * NSL; j += stride) g_flags[j] = 0;
}

// ---------------- K1: fused bidirectional LSTM recurrence ----------------
// Cooperative launch for co-residency; per-(dir,chunk) flag groups of 15 blocks,
// AGENT-scope LLC-coherent h exchange. emb staging is register-prefetched one
// step ahead into a double-buffered LDS tile -> off the critical path.
__global__ __launch_bounds__(NTHR) void k_lstm(
    const int* __restrict__ x, const float* __restrict__ emb,
    const float* __restrict__ W_ih_f, const float* __restrict__ W_hh_f, const float* __restrict__ b_f,
    const float* __restrict__ W_ih_b, const float* __restrict__ W_hh_b, const float* __restrict__ b_b)
{
    const int bi    = blockIdx.x;
    const int dir   = bi / (NCH * NSL);
    const int rem   = bi % (NCH * NSL);
    const int chunk = rem / NSL;
    const int slice = rem % NSL;
    const int j0    = slice * HS;
    const int b0    = chunk * MC;

    const float* Wih  = dir ? W_ih_b : W_ih_f;
    const float* Whh  = dir ? W_hh_b : W_hh_f;
    const float* bias = dir ? b_b    : b_f;
    unsigned short* hxd = g_hx + dir * (2 * Bn * KP);
    int* myf = g_flags + (dir * NCH + chunk) * NSL;

    __shared__ __align__(16) unsigned short Aemb[2][MC * LDK]; // 41 KB emb staging, double-buffered
    __shared__ __align__(16) unsigned short Hb[MC * LDK];      // 20.5 KB h staging
    __shared__ __align__(16) float Gsm[MC * NG];               // 10.2 KB gate dump
    __shared__ __align__(16) float Hsm[MC * HS];               // 2.5 KB h (fp32) for publish repack

    const int tid  = threadIdx.x;
    const int lane = tid & 63;
    const int wid  = tid >> 6;              // 10 waves
    const int m0   = (wid & 1) * 16;        // 2 m-tiles
    const int n0   = (wid >> 1) * 16;       // 5 n-tiles (80 gate cols)
    const int kq   = (lane >> 4) * 8;       // k-subgroup within 32

    // ---- preload weight B-fragments (fp32 -> bf16 once, weight-stationary) ----
    // local gate col layout: [i(20) | f(20) | g(20) | o(20)]
    const int nloc = n0 + (lane & 15);      // 0..79
    const int q    = nloc / HS;             // gate index 0..3
    const int jjn  = nloc % HS;
    const int grow = q * Hn + j0 + jjn;     // global row in [1200]
    s8v bih[10], bhh[10];
#pragma unroll
    for (int kc = 0; kc < 10; kc++) {
        int kb = kc * 32 + kq;
        s8v fi = {0,0,0,0,0,0,0,0}, fh = {0,0,0,0,0,0,0,0};
#pragma unroll
        for (int j = 0; j < 8; j++) {
            int k = kb + j;
            if (k < En) {
                fi[j] = (short)f2b(Wih[grow * En + k]);
                fh[j] = (short)f2b(Whh[grow * Hn + k]);
            }
        }
        bih[kc] = fi; bhh[kc] = fh;
    }

    // ---- per-thread cell state: tid <-> (batch row ebl, unit ejj); NTHR == MC*HS ----
    const int ebl = tid / HS;   // 0..31
    const int ejj = tid % HS;   // 0..19
    const float bi_i = bias[0 * Hn + j0 + ejj];
    const float bi_f = bias[1 * Hn + j0 + ejj];
    const float bi_g = bias[2 * Hn + j0 + ejj];
    const float bi_o = bias[3 * Hn + j0 + ejj];
    float creg = 0.f;

    // ---- prologue: stage emb for s=0 into Aemb[0] ----
    {
        const int t0 = dir ? (Tn - 1) : 0;
        for (int i = tid; i < MC * 80; i += NTHR) {
            int r = i / 80, c = i - r * 80;
            s4v v = {0, 0, 0, 0};
            if (c < 75) {
                int xi = x[(b0 + r) * Tn + t0];
                float4 f = *(const float4*)(emb + (size_t)xi * En + c * 4);
                v[0] = (short)f2b(f.x); v[1] = (short)f2b(f.y);
                v[2] = (short)f2b(f.z); v[3] = (short)f2b(f.w);
            }
            *(s4v*)&Aemb[0][r * LDK + c * 4] = v;
        }
    }

#pragma unroll 1
    for (int s = 0; s < Tn; s++) {
        const int t   = dir ? (Tn - 1 - s) : s;
        const int cur = s & 1, nxt = cur ^ 1;

        __syncthreads();   // Aemb[cur] staged (prologue or prev-iter writeback)

        // MFMA1: input projection part from Aemb[cur]
        f4v acc = {0.f, 0.f, 0.f, 0.f};
        {
            const unsigned short* abase = &Aemb[cur][(m0 + (lane & 15)) * LDK + kq];
#pragma unroll
            for (int kc = 0; kc < 10; kc++) {
                s8v a = *(const s8v*)(abase + kc * 32);
                acc = __builtin_amdgcn_mfma_f32_16x16x32_bf16(a, bih[kc], acc, 0, 0, 0);
            }
        }

        // issue emb prefetch for step s+1 into registers (latency hides under wait/P3/MFMA2)
        float4 pf[4];
        const bool do_pf = (s + 1 < Tn);
        if (do_pf) {
            const int tn1 = dir ? (Tn - 2 - s) : (s + 1);
#pragma unroll
            for (int k = 0; k < 4; k++) {
                int i = tid + k * NTHR;            // < 2560 = MC*80
                int r = i / 80, c = i - r * 80;
                if (c < 75) {
                    int xi = x[(b0 + r) * Tn + tn1];
                    pf[k] = *(const float4*)(emb + (size_t)xi * En + c * 4);
                }
            }
        }

        // wait: all 15 slices of this (dir,chunk) group have published h_s
        if (wid == 0 && lane < NSL) {
            while (__hip_atomic_load(&myf[lane], __ATOMIC_RELAXED, __HIP_MEMORY_SCOPE_AGENT) < s) {
                __builtin_amdgcn_s_sleep(1);
            }
        }
        __syncthreads();

        // P3: stage h_s from parity slot into Hb (LLC-coherent dword loads)
        {
            const unsigned short* hsrc = hxd + (s & 1) * (Bn * KP) + b0 * KP;
            for (int i = tid; i < MC * 160; i += NTHR) {
                int r = i / 160, c = i - r * 160;
                unsigned int v = __hip_atomic_load((const unsigned int*)(hsrc + r * KP) + c,
                                                   __ATOMIC_RELAXED, __HIP_MEMORY_SCOPE_AGENT);
                *(unsigned int*)&Hb[r * LDK + c * 2] = v;
            }
        }
        __syncthreads();

        // MFMA2: recurrent part from Hb
        {
            const unsigned short* abase = &Hb[(m0 + (lane & 15)) * LDK + kq];
#pragma unroll
            for (int kc = 0; kc < 10; kc++) {
                s8v a = *(const s8v*)(abase + kc * 32);
                acc = __builtin_amdgcn_mfma_f32_16x16x32_bf16(a, bhh[kc], acc, 0, 0, 0);
            }
        }

        // dump gates (C layout: col=lane&15, row=(lane>>4)*4+reg)
        {
            int col   = n0 + (lane & 15);
            int rbase = m0 + (lane >> 4) * 4;
#pragma unroll
            for (int r2 = 0; r2 < 4; r2++) Gsm[(rbase + r2) * NG + col] = acc[r2];
        }
        __syncthreads();

        // elementwise LSTM cell; h to Hsm (publish) and g_hcat (fire-and-forget)
        {
            float gi  = Gsm[ebl * NG + 0 * HS + ejj] + bi_i;
            float gf  = Gsm[ebl * NG + 1 * HS + ejj] + bi_f;
            float gg2 = Gsm[ebl * NG + 2 * HS + ejj] + bi_g;
            float go  = Gsm[ebl * NG + 3 * HS + ejj] + bi_o;
            float iv = sigf(gi), fv = sigf(gf), gv = tanh_f(gg2), ov = sigf(go);
            creg = fv * creg + iv * gv;
            float h = ov * tanh_f(creg);
            Hsm[ebl * HS + ejj] = h;
            g_hcat[((size_t)((b0 + ebl) * Tn + t)) * (2 * Hn) + dir * Hn + (j0 + ejj)] = f2b(h);
        }
        __syncthreads();

        // publish h_{s+1} into other parity slot as 32-bit words (slice owns 10 words/row)
        if (tid < MC * (HS / 2)) {   // 320 threads
            int r = tid / (HS / 2), w = tid % (HS / 2);
            unsigned int lo = f2b(Hsm[r * HS + 2 * w]);
            unsigned int hi = f2b(Hsm[r * HS + 2 * w + 1]);
            __hip_atomic_store((unsigned int*)(hxd + ((s + 1) & 1) * (Bn * KP)) + (b0 + r) * (KP / 2) + (j0 / 2 + w),
                               lo | (hi << 16), __ATOMIC_RELAXED, __HIP_MEMORY_SCOPE_AGENT);
        }
        __syncthreads();   // drains vmcnt -> h stores visible at LLC

        if (tid == 0) {
            __hip_atomic_store(&myf[slice], s + 1, __ATOMIC_RELEASE, __HIP_MEMORY_SCOPE_AGENT);
        }

        // writeback prefetched emb(s+1) -> Aemb[nxt] (loads completed long ago)
        if (do_pf) {
#pragma unroll
            for (int k = 0; k < 4; k++) {
                int i = tid + k * NTHR;
                int r = i / 80, c = i - r * 80;
                s4v v = {0, 0, 0, 0};
                if (c < 75) {
                    v[0] = (short)f2b(pf[k].x); v[1] = (short)f2b(pf[k].y);
                    v[2] = (short)f2b(pf[k].z); v[3] = (short)f2b(pf[k].w);
                }
                *(s4v*)&Aemb[nxt][r * LDK + c * 4] = v;
            }
        }
        // next iteration's top __syncthreads makes Aemb[nxt] visible to all
    }
}

// ---------------- K2: fused out-projection + softmax, one wave per 16 positions ----------------
__global__ __launch_bounds__(256) void k_out(
    const float* __restrict__ W_lin, const float* __restrict__ b_lin, float* __restrict__ out)
{
    __shared__ float Wl[On * 2 * Hn];  // 21.6 KB
    __shared__ float bl[On];
    const int tid = threadIdx.x;
    for (int i = tid; i < On * 2 * Hn; i += 256) Wl[i] = W_lin[i];
    if (tid < On) bl[tid] = b_lin[tid];
    __syncthreads();

    const int lane = tid & 63;
    const int w    = tid >> 6;
    const int wg   = blockIdx.x * 4 + w;      // 4096 waves
    for (int it = 0; it < 16; it++) {
        const int p = wg * 16 + it;           // 0..65535
        const unsigned short* row = g_hcat + (size_t)p * (2 * Hn);
        float part[On];
#pragma unroll
        for (int o = 0; o < On; o++) part[o] = 0.f;
        for (int c = 0; c < 10; c++) {
            int k = lane + 64 * c;
            if (k < 2 * Hn) {
                float v = b2f(row[k]);
#pragma unroll
                for (int o = 0; o < On; o++) part[o] += v * Wl[o * (2 * Hn) + k];
            }
        }
#pragma unroll
        for (int off = 32; off >= 1; off >>= 1) {
#pragma unroll
            for (int o = 0; o < On; o++) part[o] += __shfl_xor(part[o], off, 64);
        }
        if (lane == 0) {
            float lg[On];
            float m = -1e30f;
#pragma unroll
            for (int o = 0; o < On; o++) { lg[o] = part[o] + bl[o]; m = fmaxf(m, lg[o]); }
            float ssum = 0.f;
#pragma unroll
            for (int o = 0; o < On; o++) { lg[o] = __expf(lg[o] - m); ssum += lg[o]; }
            float inv = 1.f / ssum;
#pragma unroll
            for (int o = 0; o < On; o++) out[(size_t)p * On + o] = lg[o] * inv;
        }
    }
}

// ---------------- host launcher ----------------
extern "C" void kernel_launch(void* const* d_in, const int* in_sizes, int n_in,
                              void* d_out, int out_size, void* d_ws, size_t ws_size,
                              hipStream_t stream)
{
    (void)in_sizes; (void)n_in; (void)out_size; (void)d_ws; (void)ws_size;
    const int* x = (const int*)d_in[0];
    const float* emb   = (const float*)d_in[1];
    const float* Wih_f = (const float*)d_in[2];
    const float* Whh_f = (const float*)d_in[3];
    const float* bf    = (const float*)d_in[4];
    const float* Wih_b = (const float*)d_in[5];
    const float* Whh_b = (const float*)d_in[6];
    const float* bb    = (const float*)d_in[7];
    const float* Wlin  = (const float*)d_in[8];
    const float* blin  = (const float*)d_in[9];
    float* out = (float*)d_out;

    k_zero<<<128, 256, 0, stream>>>();

    void* args[] = {
        (void*)&x, (void*)&emb,
        (void*)&Wih_f, (void*)&Whh_f, (void*)&bf,
        (void*)&Wih_b, (void*)&Whh_b, (void*)&bb
    };
    hipLaunchCooperativeKernel((const void*)k_lstm, dim3(NBLK), dim3(NTHR), args, 0, stream);

    k_out<<<1024, 256, 0, stream>>>(Wlin, blin, out);
}

// Round 11
// 3160.218 us; speedup vs baseline: 4.6961x; 1.2240x over previous
//
#include <hip/hip_runtime.h>
#include <stdint.h>

// Problem dims
#define Tn 512
#define Bn 128
#define NTOK (Bn*Tn)     // 65536
#define En 300
#define Hn 300
#define On 9
#define KP 320           // K padded to 10*32
#define LDK 328          // LDS row stride in shorts (656 B rows, 16B-aligned)
#define HS 20            // hidden units per slice
#define NSL 15           // slices per direction (15*20 = 300)
#define NCH 4            // batch chunks
#define MC 32            // batch rows per chunk
#define NG 80            // 4*HS gate columns per block
#define NBLK (2*NCH*NSL) // 120 blocks
#define NTHR 640         // 10 waves = 2 m-tiles x 5 n-tiles; == MC*HS cell threads

typedef short s4v __attribute__((ext_vector_type(4)));
typedef short s8v __attribute__((ext_vector_type(8)));
typedef float f4v __attribute__((ext_vector_type(4)));

// ---- static device scratch (d_ws unused) ----
__device__ unsigned short g_hcat[NTOK * 2 * Hn];   // 78,643,200 B — h outputs (sc1 dword stores)
__device__ unsigned short g_hx[2 * 2 * Bn * KP];   //    327,680 B — [dir][slot][Bn][KP]
__device__ int            g_flags[2 * NCH * NSL];  //        480 B — per-(dir,chunk) slice flags

__device__ inline float b2f(unsigned short u){ unsigned v = ((unsigned)u) << 16; float f; __builtin_memcpy(&f, &v, 4); return f; }
__device__ inline unsigned short f2b(float f){ unsigned u; __builtin_memcpy(&u, &f, 4); u = u + 0x7fffu + ((u >> 16) & 1u); return (unsigned short)(u >> 16); }
__device__ inline float sigf(float x){ return 1.f / (1.f + __expf(-x)); }
__device__ inline float tanh_f(float x){ return 2.f / (1.f + __expf(-2.f * x)) - 1.f; }

// ---------------- K0: zero h-exchange + flags ----------------
__global__ __launch_bounds__(256) void k_zero()
{
    const int i = blockIdx.x * 256 + threadIdx.x;
    const int stride = gridDim.x * 256;
    unsigned int* hp = (unsigned int*)g_hx;
    for (int j = i; j < (2 * 2 * Bn * KP) / 2; j += stride) hp[j] = 0u;
    for (int j = i; j < 2 * NCH * NSL; j += stride) g_flags[j] = 0;
}

// ---------------- K1: fused bidirectional LSTM recurrence ----------------
// Per-(dir,chunk) flag groups of 15 blocks; ALL global stores are sc1
// (agent-relaxed atomics, write-through) so no dirty L2 lines exist and the
// per-step flag can be RELAXED (no buffer_wbl2 in the loop). 4 barriers/step.
__global__ __launch_bounds__(NTHR) void k_lstm(
    const int* __restrict__ x, const float* __restrict__ emb,
    const float* __restrict__ W_ih_f, const float* __restrict__ W_hh_f, const float* __restrict__ b_f,
    const float* __restrict__ W_ih_b, const float* __restrict__ W_hh_b, const float* __restrict__ b_b)
{
    const int bi    = blockIdx.x;
    const int dir   = bi / (NCH * NSL);
    const int rem   = bi % (NCH * NSL);
    const int chunk = rem / NSL;
    const int slice = rem % NSL;
    const int j0    = slice * HS;
    const int b0    = chunk * MC;

    const float* Wih  = dir ? W_ih_b : W_ih_f;
    const float* Whh  = dir ? W_hh_b : W_hh_f;
    const float* bias = dir ? b_b    : b_f;
    unsigned short* hxd = g_hx + dir * (2 * Bn * KP);
    int* myf = g_flags + (dir * NCH + chunk) * NSL;

    __shared__ __align__(16) unsigned short Aemb[2][MC * LDK]; // 41 KB emb staging, double-buffered
    __shared__ __align__(16) unsigned short Hb[MC * LDK];      // 20.5 KB h staging
    __shared__ __align__(16) float Gsm[MC * NG];               // 10.2 KB gate dump

    const int tid  = threadIdx.x;
    const int lane = tid & 63;
    const int wid  = tid >> 6;              // 10 waves
    const int m0   = (wid & 1) * 16;        // 2 m-tiles
    const int n0   = (wid >> 1) * 16;       // 5 n-tiles (80 gate cols)
    const int kq   = (lane >> 4) * 8;       // k-subgroup within 32

    // ---- preload weight B-fragments (fp32 -> bf16 once, weight-stationary) ----
    // local gate col layout: [i(20) | f(20) | g(20) | o(20)]
    const int nloc = n0 + (lane & 15);      // 0..79
    const int q    = nloc / HS;             // gate index 0..3
    const int jjn  = nloc % HS;
    const int grow = q * Hn + j0 + jjn;     // global row in [1200]
    s8v bih[10], bhh[10];
#pragma unroll
    for (int kc = 0; kc < 10; kc++) {
        int kb = kc * 32 + kq;
        s8v fi = {0,0,0,0,0,0,0,0}, fh = {0,0,0,0,0,0,0,0};
#pragma unroll
        for (int j = 0; j < 8; j++) {
            int k = kb + j;
            if (k < En) {
                fi[j] = (short)f2b(Wih[grow * En + k]);
                fh[j] = (short)f2b(Whh[grow * Hn + k]);
            }
        }
        bih[kc] = fi; bhh[kc] = fh;
    }

    // ---- per-thread cell state: tid <-> (batch row ebl, unit ejj); NTHR == MC*HS ----
    const int ebl = tid / HS;   // 0..31
    const int ejj = tid % HS;   // 0..19
    const float bi_i = bias[0 * Hn + j0 + ejj];
    const float bi_f = bias[1 * Hn + j0 + ejj];
    const float bi_g = bias[2 * Hn + j0 + ejj];
    const float bi_o = bias[3 * Hn + j0 + ejj];
    float creg = 0.f;
    const bool pub = ((ejj & 1) == 0);      // even-ejj lanes store packed dwords
    // pair never crosses a wave boundary: 64 = 4 (mod 20) makes boundary ejj always odd

    // ---- prologue: stage emb for s=0 into Aemb[0] ----
    {
        const int t0 = dir ? (Tn - 1) : 0;
        for (int i = tid; i < MC * 80; i += NTHR) {
            int r = i / 80, c = i - r * 80;
            s4v v = {0, 0, 0, 0};
            if (c < 75) {
                int xi = x[(b0 + r) * Tn + t0];
                float4 f = *(const float4*)(emb + (size_t)xi * En + c * 4);
                v[0] = (short)f2b(f.x); v[1] = (short)f2b(f.y);
                v[2] = (short)f2b(f.z); v[3] = (short)f2b(f.w);
            }
            *(s4v*)&Aemb[0][r * LDK + c * 4] = v;
        }
        __syncthreads();
    }

#pragma unroll 1
    for (int s = 0; s < Tn; s++) {
        const int t   = dir ? (Tn - 1 - s) : s;
        const int cur = s & 1, nxt = cur ^ 1;

        // issue emb prefetch for step s+1 into registers FIRST (max overlap)
        float4 pf[4];
        const bool do_pf = (s + 1 < Tn);
        if (do_pf) {
            const int tn1 = dir ? (Tn - 2 - s) : (s + 1);
#pragma unroll
            for (int k = 0; k < 4; k++) {
                int i = tid + k * NTHR;            // < 2560 = MC*80
                int r = i / 80, c = i - r * 80;
                if (c < 75) {
                    int xi = x[(b0 + r) * Tn + tn1];
                    pf[k] = *(const float4*)(emb + (size_t)xi * En + c * 4);
                }
            }
        }

        // MFMA1: input projection part from Aemb[cur]
        f4v acc = {0.f, 0.f, 0.f, 0.f};
        {
            const unsigned short* abase = &Aemb[cur][(m0 + (lane & 15)) * LDK + kq];
#pragma unroll
            for (int kc = 0; kc < 10; kc++) {
                s8v a = *(const s8v*)(abase + kc * 32);
                acc = __builtin_amdgcn_mfma_f32_16x16x32_bf16(a, bih[kc], acc, 0, 0, 0);
            }
        }

        // wait: all 15 slices of this (dir,chunk) group have published h_s
        if (wid == 0 && lane < NSL) {
            while (__hip_atomic_load(&myf[lane], __ATOMIC_RELAXED, __HIP_MEMORY_SCOPE_AGENT) < s) {
                __builtin_amdgcn_s_sleep(1);
            }
        }
        __syncthreads();   // bar A: wait done; MFMA1's Aemb reads complete

        // P3: stage h_s from parity slot into Hb (LLC-coherent dword loads)
        {
            const unsigned short* hsrc = hxd + (s & 1) * (Bn * KP) + b0 * KP;
            for (int i = tid; i < MC * 160; i += NTHR) {
                int r = i / 160, c = i - r * 160;
                unsigned int v = __hip_atomic_load((const unsigned int*)(hsrc + r * KP) + c,
                                                   __ATOMIC_RELAXED, __HIP_MEMORY_SCOPE_AGENT);
                *(unsigned int*)&Hb[r * LDK + c * 2] = v;
            }
        }
        __syncthreads();   // bar B: Hb ready

        // MFMA2: recurrent part from Hb
        {
            const unsigned short* abase = &Hb[(m0 + (lane & 15)) * LDK + kq];
#pragma unroll
            for (int kc = 0; kc < 10; kc++) {
                s8v a = *(const s8v*)(abase + kc * 32);
                acc = __builtin_amdgcn_mfma_f32_16x16x32_bf16(a, bhh[kc], acc, 0, 0, 0);
            }
        }

        // dump gates (C layout: col=lane&15, row=(lane>>4)*4+reg)
        {
            int col   = n0 + (lane & 15);
            int rbase = m0 + (lane >> 4) * 4;
#pragma unroll
            for (int r2 = 0; r2 < 4; r2++) Gsm[(rbase + r2) * NG + col] = acc[r2];
        }
        __syncthreads();   // bar C: Gsm ready

        // elementwise LSTM cell + fused publish (shfl-paired sc1 dword stores)
        {
            float gi  = Gsm[ebl * NG + 0 * HS + ejj] + bi_i;
            float gf  = Gsm[ebl * NG + 1 * HS + ejj] + bi_f;
            float gg2 = Gsm[ebl * NG + 2 * HS + ejj] + bi_g;
            float go  = Gsm[ebl * NG + 3 * HS + ejj] + bi_o;
            float iv = sigf(gi), fv = sigf(gf), gv = tanh_f(gg2), ov = sigf(go);
            creg = fv * creg + iv * gv;
            float h = ov * tanh_f(creg);
            float hn = __shfl_down(h, 1);          // partner (ejj+1) in same wave
            if (pub) {
                unsigned int pkt = (unsigned int)f2b(h) | ((unsigned int)f2b(hn) << 16);
                // h exchange (other parity slot)
                __hip_atomic_store((unsigned int*)(hxd + ((s + 1) & 1) * (Bn * KP))
                                       + (b0 + ebl) * (KP / 2) + (j0 + ejj) / 2,
                                   pkt, __ATOMIC_RELAXED, __HIP_MEMORY_SCOPE_AGENT);
                // hcat output (write-through keeps L2 clean)
                __hip_atomic_store((unsigned int*)g_hcat
                                       + (((size_t)((b0 + ebl) * Tn + t)) * (2 * Hn) + dir * Hn + j0 + ejj) / 2,
                                   pkt, __ATOMIC_RELAXED, __HIP_MEMORY_SCOPE_AGENT);
            }
        }

        // writeback prefetched emb(s+1) -> Aemb[nxt] (covered by bar D)
        if (do_pf) {
#pragma unroll
            for (int k = 0; k < 4; k++) {
                int i = tid + k * NTHR;
                int r = i / 80, c = i - r * 80;
                s4v v = {0, 0, 0, 0};
                if (c < 75) {
                    v[0] = (short)f2b(pf[k].x); v[1] = (short)f2b(pf[k].y);
                    v[2] = (short)f2b(pf[k].z); v[3] = (short)f2b(pf[k].w);
                }
                *(s4v*)&Aemb[nxt][r * LDK + c * 4] = v;
            }
        }
        __syncthreads();   // bar D: drains vmcnt (sc1 h stores at LLC); Aemb[nxt] visible

        // all prior stores are sc1 and drained -> RELAXED flag is sufficient (no wbl2)
        if (tid == 0) {
            __hip_atomic_store(&myf[slice], s + 1, __ATOMIC_RELAXED, __HIP_MEMORY_SCOPE_AGENT);
        }
    }
}

// ---------------- K2: fused out-projection + softmax, one wave per 16 positions ----------------
__global__ __launch_bounds__(256) void k_out(
    const float* __restrict__ W_lin, const float* __restrict__ b_lin, float* __restrict__ out)
{
    __shared__ float Wl[On * 2 * Hn];  // 21.6 KB
    __shared__ float bl[On];
    const int tid = threadIdx.x;
    for (int i = tid; i < On * 2 * Hn; i += 256) Wl[i] = W_lin[i];
    if (tid < On) bl[tid] = b_lin[tid];
    __syncthreads();

    const int lane = tid & 63;
    const int w    = tid >> 6;
    const int wg   = blockIdx.x * 4 + w;      // 4096 waves
    for (int it = 0; it < 16; it++) {
        const int p = wg * 16 + it;           // 0..65535
        const unsigned short* row = g_hcat + (size_t)p * (2 * Hn);
        float part[On];
#pragma unroll
        for (int o = 0; o < On; o++) part[o] = 0.f;
        for (int c = 0; c < 10; c++) {
            int k = lane + 64 * c;
            if (k < 2 * Hn) {
                float v = b2f(row[k]);
#pragma unroll
                for (int o = 0; o < On; o++) part[o] += v * Wl[o * (2 * Hn) + k];
            }
        }
#pragma unroll
        for (int off = 32; off >= 1; off >>= 1) {
#pragma unroll
            for (int o = 0; o < On; o++) part[o] += __shfl_xor(part[o], off, 64);
        }
        if (lane == 0) {
            float lg[On];
            float m = -1e30f;
#pragma unroll
            for (int o = 0; o < On; o++) { lg[o] = part[o] + bl[o]; m = fmaxf(m, lg[o]); }
            float ssum = 0.f;
#pragma unroll
            for (int o = 0; o < On; o++) { lg[o] = __expf(lg[o] - m); ssum += lg[o]; }
            float inv = 1.f / ssum;
#pragma unroll
            for (int o = 0; o < On; o++) out[(size_t)p * On + o] = lg[o] * inv;
        }
    }
}

// ---------------- host launcher ----------------
extern "C" void kernel_launch(void* const* d_in, const int* in_sizes, int n_in,
                              void* d_out, int out_size, void* d_ws, size_t ws_size,
                              hipStream_t stream)
{
    (void)in_sizes; (void)n_in; (void)out_size; (void)d_ws; (void)ws_size;
    const int* x = (const int*)d_in[0];
    const float* emb   = (const float*)d_in[1];
    const float* Wih_f = (const float*)d_in[2];
    const float* Whh_f = (const float*)d_in[3];
    const float* bf    = (const float*)d_in[4];
    const float* Wih_b = (const float*)d_in[5];
    const float* Whh_b = (const float*)d_in[6];
    const float* bb    = (const float*)d_in[7];
    const float* Wlin  = (const float*)d_in[8];
    const float* blin  = (const float*)d_in[9];
    float* out = (float*)d_out;

    k_zero<<<128, 256, 0, stream>>>();

    void* args[] = {
        (void*)&x, (void*)&emb,
        (void*)&Wih_f, (void*)&Whh_f, (void*)&bf,
        (void*)&Wih_b, (void*)&Whh_b, (void*)&bb
    };
    hipLaunchCooperativeKernel((const void*)k_lstm, dim3(NBLK), dim3(NTHR), args, 0, stream);

    k_out<<<1024, 256, 0, stream>>>(Wlin, blin, out);
}